// Round 9
// baseline (251.145 us; speedup 1.0000x reference)
//
#include <hip/hip_runtime.h>

typedef __attribute__((ext_vector_type(4))) float f32x4;
typedef __attribute__((ext_vector_type(2))) float f32x2;
typedef __attribute__((ext_vector_type(8))) short bf16x8;
typedef __attribute__((ext_vector_type(2))) unsigned int u32x2;
typedef unsigned short ushort_t;

#define L_DIM  256
#define H_IN_D 300
#define KP     320     // padded K for ALL stages (composed weights are 300-col)
#define BM     32      // rows per block
#define LDH    328     // h LDS row stride in ushorts (656 B)
#define NTH    256     // 4 waves; wave owns 64 output cols x all 32 rows

__device__ __forceinline__ ushort_t f2bf(float f) {
  unsigned u = __builtin_bit_cast(unsigned, f);
  unsigned r = u + 0x7fffu + ((u >> 16) & 1u);   // RNE, no NaN in data
  return (ushort_t)(r >> 16);
}
__device__ __forceinline__ unsigned pk2(float lo, float hi) {
  return (unsigned)f2bf(lo) | ((unsigned)f2bf(hi) << 16);
}

// ---------------- Mc_0 = W0 -> bf16 padded ----------------
__global__ void cvt0(const float* __restrict__ W0, ushort_t* __restrict__ Mb0) {
  int i = blockIdx.x * blockDim.x + threadIdx.x;
  if (i >= 256 * KP) return;
  int n = i / KP, k = i - n * KP;
  Mb0[i] = (k < H_IN_D) ? f2bf(W0[n * H_IN_D + k]) : (ushort_t)0;
}

// ---------------- weight composition: Mc_s = Ws @ Mc_{s-1}, c_s = Ws c_{s-1} + bs ----
__global__ __launch_bounds__(256) void comp(
    const float* __restrict__ Wmat,   // [256][256]
    const float* __restrict__ Min,    // [256][300] f32
    const float* __restrict__ bvec,   // [256]
    const float* __restrict__ cin,    // [256]
    float* __restrict__ Mout,         // [256][300] f32
    float* __restrict__ cout,         // [256]
    ushort_t* __restrict__ Mb)        // [256][320] bf16
{
  __shared__ float wrow[256];
  __shared__ float psum[4][304];
  __shared__ float red[4];
  const int n = blockIdx.x;
  const int tid = threadIdx.x;
  const int q = tid >> 6;
  const int u = tid & 63;

  float w = Wmat[n * 256 + tid];
  wrow[tid] = w;
  float cp = w * cin[tid];
  cp += __shfl_xor(cp, 1);  cp += __shfl_xor(cp, 2);  cp += __shfl_xor(cp, 4);
  cp += __shfl_xor(cp, 8);  cp += __shfl_xor(cp, 16); cp += __shfl_xor(cp, 32);
  if ((tid & 63) == 0) red[tid >> 6] = cp;
  __syncthreads();

  float a0 = 0.f, a1 = 0.f, a2 = 0.f, a3 = 0.f, a4 = 0.f;
#pragma unroll 8
  for (int jj = 0; jj < 64; ++jj) {
    int j = q * 64 + jj;
    float wj = wrow[j];
    const float* row = Min + (size_t)j * H_IN_D;
    a0 = fmaf(wj, row[u], a0);
    a1 = fmaf(wj, row[u + 64], a1);
    a2 = fmaf(wj, row[u + 128], a2);
    a3 = fmaf(wj, row[u + 192], a3);
    if (u < 44) a4 = fmaf(wj, row[u + 256], a4);
  }
  psum[q][u] = a0; psum[q][u + 64] = a1; psum[q][u + 128] = a2; psum[q][u + 192] = a3;
  if (u < 44) psum[q][u + 256] = a4;
  __syncthreads();

  {
    float s0 = psum[0][tid] + psum[1][tid] + psum[2][tid] + psum[3][tid];
    Mout[(size_t)n * H_IN_D + tid] = s0;
    Mb[n * KP + tid] = f2bf(s0);
    if (tid < 44) {
      int k = tid + 256;
      float s1 = psum[0][k] + psum[1][k] + psum[2][k] + psum[3][k];
      Mout[(size_t)n * H_IN_D + k] = s1;
      Mb[n * KP + k] = f2bf(s1);
    }
    if (tid >= 236) Mb[n * KP + (tid + 64)] = (ushort_t)0;
  }
  if (tid == 0) cout[n] = red[0] + red[1] + red[2] + red[3] + bvec[n];
}

// ---------------- fused flow kernel ----------------
// Block = 32 rows, 4 waves; wave owns 64 output cols (c0 = wave*64), all rows.
// v_s = h @ Mc_s^T + c_s (K=320).  acc[nt][mt][j] = v[mt*16+r][c0+nt*16+g*4+j]
// (nt<4, mt<2). Columns are wave-PARTITIONED (x read exactly once per block);
// y redundancy = 4 waves only. Per-row reduce: regs -> shfl(16,32) ->
// pv[4][32] partials (64 B/thread gather, broadcast reads), 1 barrier/stage.
__global__ __launch_bounds__(NTH, 3) void flow_fused(
    const float* __restrict__ z, const float* __restrict__ h,
    const ushort_t* __restrict__ Mb, const float* __restrict__ b0,
    const float* __restrict__ cvecs, float* __restrict__ out)
{
  __shared__ __align__(16) ushort_t hl[BM * LDH];   // 20992 B
  __shared__ f32x2 pv[2][4][BM];                    // 2048 B (double-buffered)

  const int tid  = threadIdx.x;
  const int wave = tid >> 6;         // 0..3
  const int lane = tid & 63;
  const int r    = lane & 15;
  const int g    = lane >> 4;        // 0..3
  const int row0 = blockIdx.x * BM;
  const int c0   = wave * 64;

  // ---- stage h -> LDS bf16, K padded 300->320 (8 rows per wave) ----
#pragma unroll
  for (int i = 0; i < 8; ++i) {
    const int row = wave * 8 + i;
    const float* hrow = h + (size_t)(row0 + row) * H_IN_D;
    f32x4 m4 = *(const f32x4*)(hrow + 4 * lane);
    u32x2 pm; pm[0] = pk2(m4[0], m4[1]); pm[1] = pk2(m4[2], m4[3]);
    *(u32x2*)&hl[row * LDH + 4 * lane] = pm;
    if (lane < 16) {
      f32x4 t4 = {0.f, 0.f, 0.f, 0.f};
      if (lane < 11) t4 = *(const f32x4*)(hrow + 256 + 4 * lane);
      u32x2 pt; pt[0] = pk2(t4[0], t4[1]); pt[1] = pk2(t4[2], t4[3]);
      *(u32x2*)&hl[row * LDH + 256 + 4 * lane] = pt;
    }
  }

  // ---- z tile -> registers, layout-matched to acc ----
  f32x4 zr[2][4];   // [mt][nt]
#pragma unroll
  for (int mt = 0; mt < 2; ++mt)
#pragma unroll
    for (int nt = 0; nt < 4; ++nt)
      zr[mt][nt] = *(const f32x4*)(z + (size_t)(row0 + mt * 16 + r) * L_DIM + c0 + nt * 16 + g * 4);

  __syncthreads();

  const ushort_t* yb = hl + r * LDH + g * 8;

#pragma unroll
  for (int s = 0; s < 4; ++s) {
    const ushort_t* W   = Mb + s * (256 * KP);
    const float*   bias = (s == 0) ? b0 : (cvecs + (s - 1) * 256);
    const int pb = s & 1;

    f32x4 acc[4][2];   // [nt][mt]
#pragma unroll
    for (int a = 0; a < 4; ++a)
#pragma unroll
      for (int b = 0; b < 2; ++b) { acc[a][b][0]=0.f; acc[a][b][1]=0.f; acc[a][b][2]=0.f; acc[a][b][3]=0.f; }

    const ushort_t* xb = W + (c0 + r) * KP + g * 8;
#pragma unroll
    for (int ks = 0; ks < 10; ++ks) {
      bf16x8 x0 = *(const bf16x8*)(xb + 0 * 16 * KP + ks * 32);
      bf16x8 x1 = *(const bf16x8*)(xb + 1 * 16 * KP + ks * 32);
      bf16x8 x2 = *(const bf16x8*)(xb + 2 * 16 * KP + ks * 32);
      bf16x8 x3 = *(const bf16x8*)(xb + 3 * 16 * KP + ks * 32);
      bf16x8 y0 = *(const bf16x8*)(yb + 0 * 16 * LDH + ks * 32);
      bf16x8 y1 = *(const bf16x8*)(yb + 1 * 16 * LDH + ks * 32);
      acc[0][0] = __builtin_amdgcn_mfma_f32_16x16x32_bf16(x0, y0, acc[0][0], 0, 0, 0);
      acc[1][0] = __builtin_amdgcn_mfma_f32_16x16x32_bf16(x1, y0, acc[1][0], 0, 0, 0);
      acc[2][0] = __builtin_amdgcn_mfma_f32_16x16x32_bf16(x2, y0, acc[2][0], 0, 0, 0);
      acc[3][0] = __builtin_amdgcn_mfma_f32_16x16x32_bf16(x3, y0, acc[3][0], 0, 0, 0);
      acc[0][1] = __builtin_amdgcn_mfma_f32_16x16x32_bf16(x0, y1, acc[0][1], 0, 0, 0);
      acc[1][1] = __builtin_amdgcn_mfma_f32_16x16x32_bf16(x1, y1, acc[1][1], 0, 0, 0);
      acc[2][1] = __builtin_amdgcn_mfma_f32_16x16x32_bf16(x2, y1, acc[2][1], 0, 0, 0);
      acc[3][1] = __builtin_amdgcn_mfma_f32_16x16x32_bf16(x3, y1, acc[3][1], 0, 0, 0);
    }

    // ---- v = acc + bias; per-row partial dots (register-local) ----
    float vz[2] = {0.f, 0.f};
    float vv[2] = {0.f, 0.f};
#pragma unroll
    for (int nt = 0; nt < 4; ++nt) {
      f32x4 bv = *(const f32x4*)(bias + c0 + nt * 16 + g * 4);
#pragma unroll
      for (int mt = 0; mt < 2; ++mt) {
#pragma unroll
        for (int j = 0; j < 4; ++j) {
          float v = acc[nt][mt][j] + bv[j];
          acc[nt][mt][j] = v;
          vz[mt] = fmaf(v, zr[mt][nt][j], vz[mt]);
          vv[mt] = fmaf(v, v, vv[mt]);
        }
      }
    }
#pragma unroll
    for (int mt = 0; mt < 2; ++mt) {
      vz[mt] += __shfl_xor(vz[mt], 16); vv[mt] += __shfl_xor(vv[mt], 16);
      vz[mt] += __shfl_xor(vz[mt], 32); vv[mt] += __shfl_xor(vv[mt], 32);
    }
    if (lane < 16) {
#pragma unroll
      for (int mt = 0; mt < 2; ++mt) {
        f32x2 p; p[0] = vz[mt]; p[1] = vv[mt];
        pv[pb][wave][mt * 16 + r] = p;
      }
    }
    __syncthreads();

    // ---- a = 2 vz/vv per row; z -= a v (register-local) ----
#pragma unroll
    for (int mt = 0; mt < 2; ++mt) {
      const int rw = mt * 16 + r;
      f32x2 t0 = pv[pb][0][rw];
      f32x2 t1 = pv[pb][1][rw];
      f32x2 t2 = pv[pb][2][rw];
      f32x2 t3 = pv[pb][3][rw];
      float sz = (t0[0] + t1[0]) + (t2[0] + t3[0]);
      float sv = (t0[1] + t1[1]) + (t2[1] + t3[1]);
      float a = 2.f * sz / sv;
#pragma unroll
      for (int nt = 0; nt < 4; ++nt)
#pragma unroll
        for (int j = 0; j < 4; ++j)
          zr[mt][nt][j] = fmaf(-a, acc[nt][mt][j], zr[mt][nt][j]);
    }
  }

  // ---- store z ----
#pragma unroll
  for (int mt = 0; mt < 2; ++mt)
#pragma unroll
    for (int nt = 0; nt < 4; ++nt)
      *(f32x4*)(out + (size_t)(row0 + mt * 16 + r) * L_DIM + c0 + nt * 16 + g * 4) = zr[mt][nt];
}

extern "C" void kernel_launch(void* const* d_in, const int* in_sizes, int n_in,
                              void* d_out, int out_size, void* d_ws, size_t ws_size,
                              hipStream_t stream) {
  const float* z  = (const float*)d_in[0];
  const float* h  = (const float*)d_in[1];
  const float* W0 = (const float*)d_in[2];
  const float* b0 = (const float*)d_in[3];
  const float* Ws = (const float*)d_in[4];
  const float* bs = (const float*)d_in[5];
  float* out = (float*)d_out;

  // ws layout
  ushort_t* Mb  = (ushort_t*)d_ws;                        // [4][256][320] bf16 = 655360 B
  float*    Mc1 = (float*)((char*)d_ws + 655360);         // [256][300] f32
  float*    Mc2 = (float*)((char*)d_ws + 962560);
  float*    Mc3 = (float*)((char*)d_ws + 1269760);
  float*    cv  = (float*)((char*)d_ws + 1576960);        // c1,c2,c3 [3][256]

  hipLaunchKernelGGL(cvt0, dim3((256 * KP + 255) / 256), dim3(256), 0, stream, W0, Mb);
  hipLaunchKernelGGL(comp, dim3(256), dim3(256), 0, stream,
                     Ws,          W0,  bs,       b0,       Mc1, cv,       Mb + 1 * 256 * KP);
  hipLaunchKernelGGL(comp, dim3(256), dim3(256), 0, stream,
                     Ws + 65536,  Mc1, bs + 256, cv,       Mc2, cv + 256, Mb + 2 * 256 * KP);
  hipLaunchKernelGGL(comp, dim3(256), dim3(256), 0, stream,
                     Ws + 131072, Mc2, bs + 512, cv + 256, Mc3, cv + 512, Mb + 3 * 256 * KP);
  hipLaunchKernelGGL(flow_fused, dim3(65536 / BM), dim3(NTH), 0, stream,
                     z, h, Mb, b0, cv, out);
}

// Round 10
// 195.197 us; speedup vs baseline: 1.2866x; 1.2866x over previous
//
#include <hip/hip_runtime.h>

typedef __attribute__((ext_vector_type(4))) float f32x4;
typedef __attribute__((ext_vector_type(2))) float f32x2;
typedef __attribute__((ext_vector_type(8))) short bf16x8;
typedef __attribute__((ext_vector_type(2))) unsigned int u32x2;
typedef __attribute__((ext_vector_type(4))) unsigned int u32x4;
typedef unsigned short ushort_t;

#define L_DIM  256
#define H_IN_D 300
#define KP     320     // padded K (composed weights are 300-col, zero-padded)
#define BM     64
#define NTH    512     // 8 waves: (wr 0..1) x (wc 0..3); wave = 32 rows x 64 cols
#define HL_STR 320     // h-tile ushort stride (640 B rows, XOR-swizzled, no pad)
#define WCH    64      // W K-chunk (rows of 128 B in LDS, XOR-swizzled)

__device__ __forceinline__ ushort_t f2bf(float f) {
  unsigned u = __builtin_bit_cast(unsigned, f);
  unsigned r = u + 0x7fffu + ((u >> 16) & 1u);   // RNE, no NaN in data
  return (ushort_t)(r >> 16);
}
__device__ __forceinline__ unsigned pk2(float lo, float hi) {
  return (unsigned)f2bf(lo) | ((unsigned)f2bf(hi) << 16);
}

// ---------------- Mc_0 = W0 -> bf16 padded ----------------
__global__ void cvt0(const float* __restrict__ W0, ushort_t* __restrict__ Mb0) {
  int i = blockIdx.x * blockDim.x + threadIdx.x;
  if (i >= 256 * KP) return;
  int n = i / KP, k = i - n * KP;
  Mb0[i] = (k < H_IN_D) ? f2bf(W0[n * H_IN_D + k]) : (ushort_t)0;
}

// ------- weight composition: Mc_s = Ws @ Mc_{s-1}, c_s = Ws c_{s-1} + bs -------
__global__ __launch_bounds__(256) void comp(
    const float* __restrict__ Wmat, const float* __restrict__ Min,
    const float* __restrict__ bvec, const float* __restrict__ cin,
    float* __restrict__ Mout, float* __restrict__ cout,
    ushort_t* __restrict__ Mb)
{
  __shared__ float wrow[256];
  __shared__ float psum[4][304];
  __shared__ float red[4];
  const int n = blockIdx.x;
  const int tid = threadIdx.x;
  const int q = tid >> 6;
  const int u = tid & 63;

  float w = Wmat[n * 256 + tid];
  wrow[tid] = w;
  float cp = w * cin[tid];
  cp += __shfl_xor(cp, 1);  cp += __shfl_xor(cp, 2);  cp += __shfl_xor(cp, 4);
  cp += __shfl_xor(cp, 8);  cp += __shfl_xor(cp, 16); cp += __shfl_xor(cp, 32);
  if ((tid & 63) == 0) red[tid >> 6] = cp;
  __syncthreads();

  float a0 = 0.f, a1 = 0.f, a2 = 0.f, a3 = 0.f, a4 = 0.f;
#pragma unroll 8
  for (int jj = 0; jj < 64; ++jj) {
    int j = q * 64 + jj;
    float wj = wrow[j];
    const float* row = Min + (size_t)j * H_IN_D;
    a0 = fmaf(wj, row[u], a0);
    a1 = fmaf(wj, row[u + 64], a1);
    a2 = fmaf(wj, row[u + 128], a2);
    a3 = fmaf(wj, row[u + 192], a3);
    if (u < 44) a4 = fmaf(wj, row[u + 256], a4);
  }
  psum[q][u] = a0; psum[q][u + 64] = a1; psum[q][u + 128] = a2; psum[q][u + 192] = a3;
  if (u < 44) psum[q][u + 256] = a4;
  __syncthreads();

  {
    float s0 = psum[0][tid] + psum[1][tid] + psum[2][tid] + psum[3][tid];
    Mout[(size_t)n * H_IN_D + tid] = s0;
    Mb[n * KP + tid] = f2bf(s0);
    if (tid < 44) {
      int k = tid + 256;
      float s1 = psum[0][k] + psum[1][k] + psum[2][k] + psum[3][k];
      Mout[(size_t)n * H_IN_D + k] = s1;
      Mb[n * KP + k] = f2bf(s1);
    }
    if (tid >= 236) Mb[n * KP + (tid + 64)] = (ushort_t)0;
  }
  if (tid == 0) cout[n] = red[0] + red[1] + red[2] + red[3] + bvec[n];
}

// ---------------- fused flow kernel (m97-style staged W) ----------------
// v_s = h @ Mc_s^T + c_s (K=320, 5 chunks of 64). W chunk LDS [256][64] ushorts
// (128-B rows) + h tile [64][320], both XOR-swizzled: byte ^= ((row&7)<<4),
// applied on BOTH write and read (reg-staged => both sides swizzlable).
// acc[nt][mt][j] = v[wr*32+mt*16+r][wc*64+nt*16+g*4+j]; zr mirrors acc.
__global__ __launch_bounds__(NTH, 2) void flow_fused(
    const float* __restrict__ z, const float* __restrict__ h,
    const ushort_t* __restrict__ Mb, const float* __restrict__ b0,
    const float* __restrict__ cvecs, float* __restrict__ out)
{
  __shared__ __align__(16) ushort_t hl[BM * HL_STR];       // 40960 B
  __shared__ __align__(16) ushort_t Wl[2][256 * WCH];      // 2 x 32768 B
  __shared__ f32x2 pv[2][4][BM];                           // 4096 B

  const int tid  = threadIdx.x;
  const int wave = tid >> 6;        // 0..7
  const int lane = tid & 63;
  const int r    = lane & 15;
  const int g    = lane >> 4;       // 0..3
  const int wr   = wave >> 2;       // row half 0..1
  const int wc   = wave & 3;        // col quarter 0..3
  // XCD-aware bijective swizzle (1024 % 8 == 0)
  const int bid  = blockIdx.x;
  const int wg   = (bid & 7) * 128 + (bid >> 3);
  const int row0 = wg * BM;
  const unsigned swz = (unsigned)((r & 7) << 4);

  // ---- stage h -> LDS bf16 (swizzled), K padded 300->320 ----
#pragma unroll
  for (int i = 0; i < 8; ++i) {
    const int row = wave * 8 + i;
    const float* hrow = h + (size_t)(row0 + row) * H_IN_D;
    const unsigned rs = (unsigned)((row & 7) << 4);
    f32x4 m4 = *(const f32x4*)(hrow + 4 * lane);
    u32x2 pm; pm[0] = pk2(m4[0], m4[1]); pm[1] = pk2(m4[2], m4[3]);
    *(u32x2*)((char*)hl + (((unsigned)(row * 640 + lane * 8)) ^ rs)) = pm;
    if (lane < 16) {
      f32x4 t4 = {0.f, 0.f, 0.f, 0.f};
      if (lane < 11) t4 = *(const f32x4*)(hrow + 256 + 4 * lane);
      u32x2 pt; pt[0] = pk2(t4[0], t4[1]); pt[1] = pk2(t4[2], t4[3]);
      *(u32x2*)((char*)hl + (((unsigned)(row * 640 + 512 + lane * 8)) ^ rs)) = pt;
    }
  }

  // ---- z tile -> registers (layout-matched to acc) ----
  f32x4 zr[2][4];   // [mt][nt]
#pragma unroll
  for (int mt = 0; mt < 2; ++mt)
#pragma unroll
    for (int nt = 0; nt < 4; ++nt)
      zr[mt][nt] = *(const f32x4*)(z + (size_t)(row0 + wr * 32 + mt * 16 + r) * L_DIM
                                   + wc * 64 + nt * 16 + g * 4);

  // ---- staging helpers (per thread: 64 B of a 32 KB chunk) ----
  const int sn   = tid >> 1;            // W row 0..255
  const int half = tid & 1;             // 64-B half-row
  const unsigned wswz = (unsigned)((sn & 7) << 4);
  const unsigned dst0 = (unsigned)(sn * 128 + half * 64);

  u32x4 v0, v1, v2, v3;
#define LD_CHUNK(S, C) do {                                                   \
    const ushort_t* _src = Mb + (S) * (256 * KP) + sn * KP + (C) * WCH + half * 32; \
    v0 = *(const u32x4*)(_src + 0);  v1 = *(const u32x4*)(_src + 8);          \
    v2 = *(const u32x4*)(_src + 16); v3 = *(const u32x4*)(_src + 24);         \
  } while (0)
#define ST_CHUNK(BUF) do {                                                    \
    char* _d = (char*)(BUF);                                                  \
    *(u32x4*)(_d + ((dst0 +  0) ^ wswz)) = v0;                                \
    *(u32x4*)(_d + ((dst0 + 16) ^ wswz)) = v1;                                \
    *(u32x4*)(_d + ((dst0 + 32) ^ wswz)) = v2;                                \
    *(u32x4*)(_d + ((dst0 + 48) ^ wswz)) = v3;                                \
  } while (0)

  // prologue: stage s=0 chunk 0 (barrier below also covers h staging)
  LD_CHUNK(0, 0);
  ST_CHUNK(Wl[0]);
  __syncthreads();

#pragma unroll
  for (int s = 0; s < 4; ++s) {
    const float* bias = (s == 0) ? b0 : (cvecs + (s - 1) * 256);
    const int pb = s & 1;

    f32x4 acc[4][2];   // [nt][mt]
#pragma unroll
    for (int a = 0; a < 4; ++a)
#pragma unroll
      for (int b = 0; b < 2; ++b) { acc[a][b][0]=0.f; acc[a][b][1]=0.f; acc[a][b][2]=0.f; acc[a][b][3]=0.f; }

#pragma unroll
    for (int c = 0; c < 5; ++c) {
      // issue next staging loads early (T14: issue-early / write-late)
      if (c < 4)            LD_CHUNK(s, c + 1);
      else if (s < 3)       LD_CHUNK(s + 1, 0);

      const char* wb = (const char*)Wl[c & 1];
#pragma unroll
      for (int ks = 0; ks < 2; ++ks) {
        bf16x8 x[4];
#pragma unroll
        for (int nt = 0; nt < 4; ++nt)
          x[nt] = *(const bf16x8*)(wb + (((unsigned)((wc * 64 + nt * 16 + r) * 128 + ks * 64 + g * 16)) ^ swz));
        bf16x8 y[2];
#pragma unroll
        for (int mt = 0; mt < 2; ++mt)
          y[mt] = *(const bf16x8*)((const char*)hl
                    + (unsigned)((wr * 32 + mt * 16 + r) * 640 + c * 128)
                    + (((unsigned)(ks * 64 + g * 16)) ^ swz));
#pragma unroll
        for (int nt = 0; nt < 4; ++nt) {
          acc[nt][0] = __builtin_amdgcn_mfma_f32_16x16x32_bf16(x[nt], y[0], acc[nt][0], 0, 0, 0);
          acc[nt][1] = __builtin_amdgcn_mfma_f32_16x16x32_bf16(x[nt], y[1], acc[nt][1], 0, 0, 0);
        }
      }

      if (c < 4) { ST_CHUNK(Wl[(c + 1) & 1]); __syncthreads(); }
    }

    // ---- v = acc + bias; per-row partial dots ----
    float vz[2] = {0.f, 0.f};
    float vv[2] = {0.f, 0.f};
#pragma unroll
    for (int nt = 0; nt < 4; ++nt) {
      f32x4 bv = *(const f32x4*)(bias + wc * 64 + nt * 16 + g * 4);
#pragma unroll
      for (int mt = 0; mt < 2; ++mt) {
#pragma unroll
        for (int j = 0; j < 4; ++j) {
          float v = acc[nt][mt][j] + bv[j];
          acc[nt][mt][j] = v;
          vz[mt] = fmaf(v, zr[mt][nt][j], vz[mt]);
          vv[mt] = fmaf(v, v, vv[mt]);
        }
      }
    }
#pragma unroll
    for (int mt = 0; mt < 2; ++mt) {
      vz[mt] += __shfl_xor(vz[mt], 16); vv[mt] += __shfl_xor(vv[mt], 16);
      vz[mt] += __shfl_xor(vz[mt], 32); vv[mt] += __shfl_xor(vv[mt], 32);
    }
    if (lane < 16) {
#pragma unroll
      for (int mt = 0; mt < 2; ++mt) {
        f32x2 p; p[0] = vz[mt]; p[1] = vv[mt];
        pv[pb][wc][wr * 32 + mt * 16 + r] = p;
      }
    }
    __syncthreads();   // pv visible; also releases WAR on Wl[0] (chunk 4 done)

    // stage next stage's chunk 0 (loaded during c=4 above)
    if (s < 3) ST_CHUNK(Wl[0]);

    // ---- a = 2 vz/vv per row; z -= a v ----
#pragma unroll
    for (int mt = 0; mt < 2; ++mt) {
      const int rw = wr * 32 + mt * 16 + r;
      f32x2 t0 = pv[pb][0][rw], t1 = pv[pb][1][rw];
      f32x2 t2 = pv[pb][2][rw], t3 = pv[pb][3][rw];
      float sz = (t0[0] + t1[0]) + (t2[0] + t3[0]);
      float sv = (t0[1] + t1[1]) + (t2[1] + t3[1]);
      float a = 2.f * sz / sv;
#pragma unroll
      for (int nt = 0; nt < 4; ++nt)
#pragma unroll
        for (int j = 0; j < 4; ++j)
          zr[mt][nt][j] = fmaf(-a, acc[nt][mt][j], zr[mt][nt][j]);
    }

    if (s < 3) __syncthreads();   // chunk 0 of next stage visible
  }

  // ---- store z ----
#pragma unroll
  for (int mt = 0; mt < 2; ++mt)
#pragma unroll
    for (int nt = 0; nt < 4; ++nt)
      *(f32x4*)(out + (size_t)(row0 + wr * 32 + mt * 16 + r) * L_DIM
                + wc * 64 + nt * 16 + g * 4) = zr[mt][nt];
#undef LD_CHUNK
#undef ST_CHUNK
}

extern "C" void kernel_launch(void* const* d_in, const int* in_sizes, int n_in,
                              void* d_out, int out_size, void* d_ws, size_t ws_size,
                              hipStream_t stream) {
  const float* z  = (const float*)d_in[0];
  const float* h  = (const float*)d_in[1];
  const float* W0 = (const float*)d_in[2];
  const float* b0 = (const float*)d_in[3];
  const float* Ws = (const float*)d_in[4];
  const float* bs = (const float*)d_in[5];
  float* out = (float*)d_out;

  ushort_t* Mb  = (ushort_t*)d_ws;                        // [4][256][320] bf16
  float*    Mc1 = (float*)((char*)d_ws + 655360);         // [256][300] f32
  float*    Mc2 = (float*)((char*)d_ws + 962560);
  float*    Mc3 = (float*)((char*)d_ws + 1269760);
  float*    cv  = (float*)((char*)d_ws + 1576960);        // c1,c2,c3 [3][256]

  hipLaunchKernelGGL(cvt0, dim3((256 * KP + 255) / 256), dim3(256), 0, stream, W0, Mb);
  hipLaunchKernelGGL(comp, dim3(256), dim3(256), 0, stream,
                     Ws,          W0,  bs,       b0,       Mc1, cv,       Mb + 1 * 256 * KP);
  hipLaunchKernelGGL(comp, dim3(256), dim3(256), 0, stream,
                     Ws + 65536,  Mc1, bs + 256, cv,       Mc2, cv + 256, Mb + 2 * 256 * KP);
  hipLaunchKernelGGL(comp, dim3(256), dim3(256), 0, stream,
                     Ws + 131072, Mc2, bs + 512, cv + 256, Mc3, cv + 512, Mb + 3 * 256 * KP);
  hipLaunchKernelGGL(flow_fused, dim3(65536 / BM), dim3(NTH), 0, stream,
                     z, h, Mb, b0, cv, out);
}